// Round 4
// baseline (902.835 us; speedup 1.0000x reference)
//
#include <hip/hip_runtime.h>

#define N_NODES   100000
#define N_FEAT    128
#define N_EDGES   1600000
#define HIDDEN    64
#define NUM_GRAPHS 64
#define CHUNK   4096
#define NCHUNK  ((N_EDGES + CHUNK - 1) / CHUNK)   // 391 chunks of 4096 edges
#define BSHIFT  8
#define NBUCKET ((N_NODES + 255) >> 8)            // 391 buckets of 256 nodes
#define OFFS_W  (NBUCKET + 1)                     // 392 entries per chunk
#define WT_BLOCKS 4
#define GEMM_GRID ((N_NODES + 127) / 128)         // 782 blocks of 128 rows

typedef unsigned int  uint32;
typedef unsigned short ushort16;

typedef __attribute__((ext_vector_type(8))) __bf16 bf16x8;
typedef __attribute__((ext_vector_type(4))) float  f32x4;
union Frag8 { bf16x8 v; unsigned short s[8]; uint4 q; };

// fp32 -> bf16 round-to-nearest-even
static __device__ __forceinline__ unsigned short f2bf(float f) {
    uint32 u = __float_as_uint(f);
    u += 0x7fffu + ((u >> 16) & 1u);
    return (unsigned short)(u >> 16);
}

// ---------------------------------------------------------------------------
// L1: blocks [0,4)   : Wt[n][k] = bf16(W[k][n])
//     blocks [4,395) : partition edges into 391 dst-buckets per 4096-edge
//                      chunk via LDS; ALSO counts per-node in-degree via
//                      fire-and-forget global atomics (deg feeds the gemm
//                      epilogue's dis pre-scale next kernel).
// ---------------------------------------------------------------------------
__global__ __launch_bounds__(512) void k_pre(const float* __restrict__ W,
                                             ushort16* __restrict__ Wt,
                                             const int* __restrict__ ei,
                                             int* __restrict__ src_out,
                                             unsigned char* __restrict__ dst8,
                                             int* __restrict__ offs,
                                             int* __restrict__ deg) {
    __shared__ int hist[512];
    __shared__ int excl[512];
    __shared__ int ssrc[CHUNK];     // 16 KB
    __shared__ int sdst[CHUNK];     // 16 KB

    if (blockIdx.x < WT_BLOCKS) {   // ---- w_transpose: 128*64 = 8192 elems
        const int base = blockIdx.x * 2048 + threadIdx.x;
#pragma unroll
        for (int j = 0; j < 4; ++j) {
            const int idx = base + j * 512;
            const int k = idx >> 6, n = idx & 63;
            Wt[n * N_FEAT + k] = f2bf(W[idx]);
        }
        return;
    }

    // ---- partition ----
    const int c = blockIdx.x - WT_BLOCKS;
    const int base = c * CHUNK;
    const int n = min(CHUNK, N_EDGES - base);   // always a multiple of 4
    const int t = threadIdx.x;
    hist[t] = 0;
    __syncthreads();

    int es[CHUNK / 512], ed[CHUNK / 512], rk[CHUNK / 512];
#pragma unroll
    for (int k = 0; k < CHUNK / 512; ++k) {
        const int i = t + k * 512;
        if (i < n) {
            ed[k] = __builtin_nontemporal_load(&ei[N_EDGES + base + i]);
            es[k] = __builtin_nontemporal_load(&ei[base + i]);
            rk[k] = atomicAdd(&hist[ed[k] >> BSHIFT], 1);
            atomicAdd(&deg[ed[k]], 1);          // fire-and-forget in-degree
        }
    }
    __syncthreads();

    const int cnt = hist[t];
    for (int off = 1; off < 512; off <<= 1) {
        const int v = (t >= off) ? hist[t - off] : 0;
        __syncthreads();
        hist[t] += v;
        __syncthreads();
    }
    excl[t] = hist[t] - cnt;
    __syncthreads();
    if (t <= NBUCKET) offs[c * OFFS_W + t] = base + excl[t];   // excl[NBUCKET]==n

#pragma unroll
    for (int k = 0; k < CHUNK / 512; ++k) {
        const int i = t + k * 512;
        if (i < n) {
            const int pos = excl[ed[k] >> BSHIFT] + rk[k];
            ssrc[pos] = es[k];
            sdst[pos] = ed[k];
        }
    }
    __syncthreads();

    for (int i = t; i < n; i += 512)
        src_out[base + i] = ssrc[i];
    for (int i = t * 4; i < n; i += 2048) {
        const uint32 p = (uint32)(sdst[i] & 255)
                       | ((uint32)(sdst[i + 1] & 255) << 8)
                       | ((uint32)(sdst[i + 2] & 255) << 16)
                       | ((uint32)(sdst[i + 3] & 255) << 24);
        *(uint32*)&dst8[base + i] = p;
    }
}

// ---------------------------------------------------------------------------
// K1: hb = bf16( (x @ W) * rsqrt(deg+1) )  — pure BW-bound MFMA gemm with the
// dis scale fused into the epilogue (deg known from k_pre's atomics).
// ---------------------------------------------------------------------------
__global__ __launch_bounds__(512) void k_gemm(const float* __restrict__ x,
                                              const ushort16* __restrict__ Wt,
                                              const int* __restrict__ deg,
                                              ushort16* __restrict__ hb) {
    const int t    = threadIdx.x;
    const int lane = t & 63;
    const int wv   = t >> 6;                              // 0..7
    const int m15  = lane & 15;
    const int quad = lane >> 4;
    const int base = blockIdx.x * 128 + wv * 16;
    const int arow = min(base + m15, N_NODES - 1);        // clamp tail

    const float* xr = &x[(size_t)arow * N_FEAT + quad * 8];
    float4 xa[4][2];
#pragma unroll
    for (int kc = 0; kc < 4; ++kc) {
        xa[kc][0] = *(const float4*)&xr[kc * 32];
        xa[kc][1] = *(const float4*)&xr[kc * 32 + 4];
    }

    Frag8 bf[4][4];
#pragma unroll
    for (int nt = 0; nt < 4; ++nt) {
        const ushort16* wr = &Wt[(nt * 16 + m15) * N_FEAT + quad * 8];
#pragma unroll
        for (int kc = 0; kc < 4; ++kc)
            bf[nt][kc].q = *(const uint4*)&wr[kc * 32];
    }

    Frag8 af[4];
#pragma unroll
    for (int kc = 0; kc < 4; ++kc) {
        const float* f = (const float*)&xa[kc][0];
#pragma unroll
        for (int j = 0; j < 8; ++j) af[kc].s[j] = f2bf(f[j]);
    }

    f32x4 acc[4];
#pragma unroll
    for (int nt = 0; nt < 4; ++nt) acc[nt] = (f32x4){0.f, 0.f, 0.f, 0.f};

#pragma unroll
    for (int kc = 0; kc < 4; ++kc)
#pragma unroll
        for (int nt = 0; nt < 4; ++nt)
            acc[nt] = __builtin_amdgcn_mfma_f32_16x16x32_bf16(af[kc].v, bf[nt][kc].v,
                                                              acc[nt], 0, 0, 0);

    // epilogue: rows base+quad*4+{0..3}; deg int4 (reads past deg end are
    // inside workspace -> safe; stores guarded)
    const int4 dg = *(const int4*)&deg[base + quad * 4];
    float dn[4];
    dn[0] = rsqrtf((float)dg.x + 1.f);
    dn[1] = rsqrtf((float)dg.y + 1.f);
    dn[2] = rsqrtf((float)dg.z + 1.f);
    dn[3] = rsqrtf((float)dg.w + 1.f);

#pragma unroll
    for (int r = 0; r < 4; ++r) {
        const int orow = base + quad * 4 + r;
        if (orow < N_NODES) {
#pragma unroll
            for (int nt = 0; nt < 4; ++nt)
                hb[(size_t)orow * HIDDEN + nt * 16 + m15] = f2bf(acc[nt][r] * dn[r]);
        }
    }
}

// ---------------------------------------------------------------------------
// K2: fused aggregate — one block per 256-node bucket. Streams the bucket's
// 391 chunk-segments straight from the partition output into a 256x64 fp32
// LDS accumulator (ds_add_f32). Replaces bucket_csr + srcs r/w + old agg +
// k_scale. Per-8-lane-group chunk cursor: no scans, no binary search.
// Epilogue: relu(dn*(acc + hs_self) + b), then sorted-batch pooling into u.
// ---------------------------------------------------------------------------
__global__ __launch_bounds__(512) void k_agg(const int* __restrict__ offs,
                                             const int* __restrict__ src_tmp,
                                             const unsigned char* __restrict__ dst8,
                                             const ushort16* __restrict__ hb,
                                             const int* __restrict__ deg,
                                             const float* __restrict__ bias,
                                             const int* __restrict__ batch,
                                             float* __restrict__ u) {
    __shared__ float sacc[256 * 65];    // 66.56 KB, stride 65 breaks bank aliasing
    __shared__ int   segb[NCHUNK];
    __shared__ int   slen[NCHUNK];
    __shared__ int   gbs[256];
    __shared__ float sdn[256];
    const int b  = blockIdx.x;
    const int lo = b << BSHIFT;
    const int t  = threadIdx.x;

    if (t < NCHUNK) {
        const int s0 = offs[t * OFFS_W + b];
        segb[t] = s0;
        slen[t] = offs[t * OFFS_W + b + 1] - s0;
    }
    for (int i = t; i < 256 * 65; i += 512) sacc[i] = 0.f;
    if (t < 256) {
        const int node = lo + t;
        const bool ok = node < N_NODES;
        gbs[t] = ok ? batch[node] : 0;
        sdn[t] = ok ? rsqrtf((float)deg[node] + 1.f) : 0.f;
    }
    __syncthreads();

    // ---- edge loop: group g (8 lanes) walks chunks g, g+64, ... ----
    const int grp = t >> 3;             // 0..63
    const int k   = t & 7;
    int c  = grp;
    int s0 = segb[c];
    int L  = slen[c];
    int i  = 0;
    while (true) {
        while (i >= L) {                // advance to next owned chunk
            c += 64;
            if (c >= NCHUNK) break;
            s0 = segb[c]; L = slen[c]; i = 0;
        }
        if (c >= NCHUNK) break;
        const int gidx = s0 + i;
        const int src  = src_tmp[gidx];        // uniform across the 8 lanes
        const int d    = dst8[gidx];
        const uint4 v  = *(const uint4*)&hb[(size_t)src * HIDDEN + k * 8];
        float* a = &sacc[d * 65 + k * 8];
        atomicAdd(&a[0], __uint_as_float(v.x << 16));
        atomicAdd(&a[1], __uint_as_float(v.x & 0xffff0000u));
        atomicAdd(&a[2], __uint_as_float(v.y << 16));
        atomicAdd(&a[3], __uint_as_float(v.y & 0xffff0000u));
        atomicAdd(&a[4], __uint_as_float(v.z << 16));
        atomicAdd(&a[5], __uint_as_float(v.z & 0xffff0000u));
        atomicAdd(&a[6], __uint_as_float(v.w << 16));
        atomicAdd(&a[7], __uint_as_float(v.w & 0xffff0000u));
        ++i;
    }
    __syncthreads();

    // ---- epilogue: relu + pool. thread = (feature f, node-segment seg) ----
    const int f   = t & 63;
    const int seg = t >> 6;             // 0..7, 32 nodes each
    const unsigned short* hrow = (const unsigned short*)hb;
    const float bf_ = bias[f];
    float a = 0.f;
    int   cg = -1;
    for (int n = seg * 32; n < seg * 32 + 32; ++n) {
        const int node = lo + n;
        if (node >= N_NODES) break;
        const float self = __uint_as_float((uint32)hrow[(size_t)node * HIDDEN + f] << 16);
        const float r = fmaxf(fmaf(sacc[n * 65 + f] + self, sdn[n], bf_), 0.f);
        const int gr = gbs[n];
        if (gr != cg) {
            if (cg >= 0) atomicAdd(&u[cg * HIDDEN + f], a);
            cg = gr; a = r;
        } else {
            a += r;
        }
    }
    if (cg >= 0) atomicAdd(&u[cg * HIDDEN + f], a);
}

// ---------------------------------------------------------------------------
// K3: out[g] = relu(u[g] @ W1 + b1) @ W2 + b2
// ---------------------------------------------------------------------------
__global__ __launch_bounds__(64) void mlp_kernel(const float* __restrict__ u,
                                                 const float* __restrict__ W1,
                                                 const float* __restrict__ b1,
                                                 const float* __restrict__ W2,
                                                 const float* __restrict__ b2,
                                                 float* __restrict__ out) {
    __shared__ float W1s[HIDDEN * 16];
    __shared__ float W2s[16];
    __shared__ float b1s[16];
    const int t = threadIdx.x;
    for (int i = t; i < HIDDEN * 16; i += 64) W1s[i] = W1[i];
    if (t < 16) { W2s[t] = W2[t]; b1s[t] = b1[t]; }
    __syncthreads();
    if (t < NUM_GRAPHS) {
        float uu[HIDDEN];
#pragma unroll
        for (int k = 0; k < HIDDEN; ++k) uu[k] = u[t * HIDDEN + k];
        float o = b2[0];
#pragma unroll
        for (int j = 0; j < 16; ++j) {
            float s = b1s[j];
#pragma unroll
            for (int k = 0; k < HIDDEN; ++k) s = fmaf(uu[k], W1s[k * 16 + j], s);
            o = fmaf(fmaxf(s, 0.f), W2s[j], o);
        }
        out[t] = o;
    }
}

// ---------------------------------------------------------------------------
extern "C" void kernel_launch(void* const* d_in, const int* in_sizes, int n_in,
                              void* d_out, int out_size, void* d_ws, size_t ws_size,
                              hipStream_t stream) {
    const float* x  = (const float*)d_in[0];
    const float* W  = (const float*)d_in[1];
    const float* b  = (const float*)d_in[2];
    const float* W1 = (const float*)d_in[3];
    const float* b1 = (const float*)d_in[4];
    const float* W2 = (const float*)d_in[5];
    const float* b2 = (const float*)d_in[6];
    const int*   ei = (const int*)d_in[7];     // [2, E] flat
    const int* batch = (const int*)d_in[8];    // [N], sorted
    float* out = (float*)d_out;

    ushort16* hb       = (ushort16*)d_ws;                        // 12.8 MB
    int*      src_tmp  = (int*)(hb + (size_t)N_NODES * HIDDEN);  // 6.4 MB
    unsigned char* dst8 = (unsigned char*)(src_tmp + N_EDGES);   // 1.6 MB
    int*      offs     = (int*)(dst8 + N_EDGES);                 // 613 KB
    float*    u        = (float*)(offs + NCHUNK * OFFS_W);       // 16 KB
    int*      deg      = (int*)(u + NUM_GRAPHS * HIDDEN);        // 400 KB
    ushort16* Wtg      = (ushort16*)(deg + N_NODES);             // 16 KB

    // zero u (pool accumulators) + deg (atomic degree counters) in one memset
    hipMemsetAsync(u, 0, (NUM_GRAPHS * HIDDEN + N_NODES) * sizeof(float), stream);

    k_pre<<<WT_BLOCKS + NCHUNK, 512, 0, stream>>>(W, Wtg, ei, src_tmp, dst8, offs, deg);
    k_gemm<<<GEMM_GRID, 512, 0, stream>>>(x, Wtg, deg, hb);
    k_agg<<<NBUCKET, 512, 0, stream>>>(offs, src_tmp, dst8, hb, deg, b, batch, u);
    mlp_kernel<<<1, 64, 0, stream>>>(u, W1, b1, W2, b2, out);
}

// Round 5
// 892.342 us; speedup vs baseline: 1.0118x; 1.0118x over previous
//
#include <hip/hip_runtime.h>

#define N_NODES   100000
#define N_FEAT    128
#define N_EDGES   1600000
#define HIDDEN    64
#define NUM_GRAPHS 64
#define CHUNK   4096
#define NCHUNK  ((N_EDGES + CHUNK - 1) / CHUNK)   // 391 chunks of 4096 edges
#define BSHIFT  8
#define NBUCKET ((N_NODES + 255) >> 8)            // 391 buckets of 256 nodes
#define OFFS_W  (NBUCKET + 1)                     // 392 entries per chunk
#define WT_BLOCKS 4
#define GEMM_GRID ((N_NODES + 127) / 128)         // 782 blocks of 128 rows

typedef unsigned int  uint32;
typedef unsigned short ushort16;

typedef __attribute__((ext_vector_type(8))) __bf16 bf16x8;
typedef __attribute__((ext_vector_type(4))) float  f32x4;
union Frag8 { bf16x8 v; unsigned short s[8]; uint4 q; };

// fp32 -> bf16 round-to-nearest-even
static __device__ __forceinline__ unsigned short f2bf(float f) {
    uint32 u = __float_as_uint(f);
    u += 0x7fffu + ((u >> 16) & 1u);
    return (unsigned short)(u >> 16);
}

// ---------------------------------------------------------------------------
// L1: blocks [0,4)   : Wt[n][k] = bf16(W[k][n])
//     blocks [4,395) : partition edges into 391 dst-buckets per 4096-edge
//                      chunk via LDS. deg atomics now issued from the
//                      BUCKET-SORTED writeout (consecutive lanes hit the same
//                      ~1KB node window -> L2 line combining), not from the
//                      random-order load phase (round-4 regression).
// ---------------------------------------------------------------------------
__global__ __launch_bounds__(512) void k_pre(const float* __restrict__ W,
                                             ushort16* __restrict__ Wt,
                                             const int* __restrict__ ei,
                                             int* __restrict__ src_out,
                                             unsigned char* __restrict__ dst8,
                                             int* __restrict__ offs,
                                             int* __restrict__ deg) {
    __shared__ int hist[512];
    __shared__ int excl[512];
    __shared__ int ssrc[CHUNK];     // 16 KB
    __shared__ int sdst[CHUNK];     // 16 KB

    if (blockIdx.x < WT_BLOCKS) {   // ---- w_transpose: 128*64 = 8192 elems
        const int base = blockIdx.x * 2048 + threadIdx.x;
#pragma unroll
        for (int j = 0; j < 4; ++j) {
            const int idx = base + j * 512;
            const int k = idx >> 6, n = idx & 63;
            Wt[n * N_FEAT + k] = f2bf(W[idx]);
        }
        return;
    }

    // ---- partition ----
    const int c = blockIdx.x - WT_BLOCKS;
    const int base = c * CHUNK;
    const int n = min(CHUNK, N_EDGES - base);   // always a multiple of 4
    const int t = threadIdx.x;
    hist[t] = 0;
    __syncthreads();

    int es[CHUNK / 512], ed[CHUNK / 512], rk[CHUNK / 512];
#pragma unroll
    for (int k = 0; k < CHUNK / 512; ++k) {
        const int i = t + k * 512;
        if (i < n) {
            ed[k] = __builtin_nontemporal_load(&ei[N_EDGES + base + i]);
            es[k] = __builtin_nontemporal_load(&ei[base + i]);
            rk[k] = atomicAdd(&hist[ed[k] >> BSHIFT], 1);
        }
    }
    __syncthreads();

    const int cnt = hist[t];
    for (int off = 1; off < 512; off <<= 1) {
        const int v = (t >= off) ? hist[t - off] : 0;
        __syncthreads();
        hist[t] += v;
        __syncthreads();
    }
    excl[t] = hist[t] - cnt;
    __syncthreads();
    if (t <= NBUCKET) offs[c * OFFS_W + t] = base + excl[t];   // excl[NBUCKET]==n

#pragma unroll
    for (int k = 0; k < CHUNK / 512; ++k) {
        const int i = t + k * 512;
        if (i < n) {
            const int pos = excl[ed[k] >> BSHIFT] + rk[k];
            ssrc[pos] = es[k];
            sdst[pos] = ed[k];
        }
    }
    __syncthreads();

    for (int i = t; i < n; i += 512) {
        src_out[base + i] = ssrc[i];
        atomicAdd(&deg[sdst[i]], 1);      // bucket-sorted order: L2-local RMW
    }
    for (int i = t * 4; i < n; i += 2048) {
        const uint32 p = (uint32)(sdst[i] & 255)
                       | ((uint32)(sdst[i + 1] & 255) << 8)
                       | ((uint32)(sdst[i + 2] & 255) << 16)
                       | ((uint32)(sdst[i + 3] & 255) << 24);
        *(uint32*)&dst8[base + i] = p;
    }
}

// ---------------------------------------------------------------------------
// K1: hb = bf16( (x @ W) * rsqrt(deg+1) )  — pure BW-bound MFMA gemm with the
// dis scale fused into the epilogue (deg known from k_pre's atomics).
// ---------------------------------------------------------------------------
__global__ __launch_bounds__(512) void k_gemm(const float* __restrict__ x,
                                              const ushort16* __restrict__ Wt,
                                              const int* __restrict__ deg,
                                              ushort16* __restrict__ hb) {
    const int t    = threadIdx.x;
    const int lane = t & 63;
    const int wv   = t >> 6;                              // 0..7
    const int m15  = lane & 15;
    const int quad = lane >> 4;
    const int base = blockIdx.x * 128 + wv * 16;
    const int arow = min(base + m15, N_NODES - 1);        // clamp tail

    const float* xr = &x[(size_t)arow * N_FEAT + quad * 8];
    float4 xa[4][2];
#pragma unroll
    for (int kc = 0; kc < 4; ++kc) {
        xa[kc][0] = *(const float4*)&xr[kc * 32];
        xa[kc][1] = *(const float4*)&xr[kc * 32 + 4];
    }

    Frag8 bf[4][4];
#pragma unroll
    for (int nt = 0; nt < 4; ++nt) {
        const ushort16* wr = &Wt[(nt * 16 + m15) * N_FEAT + quad * 8];
#pragma unroll
        for (int kc = 0; kc < 4; ++kc)
            bf[nt][kc].q = *(const uint4*)&wr[kc * 32];
    }

    Frag8 af[4];
#pragma unroll
    for (int kc = 0; kc < 4; ++kc) {
        const float* f = (const float*)&xa[kc][0];
#pragma unroll
        for (int j = 0; j < 8; ++j) af[kc].s[j] = f2bf(f[j]);
    }

    f32x4 acc[4];
#pragma unroll
    for (int nt = 0; nt < 4; ++nt) acc[nt] = (f32x4){0.f, 0.f, 0.f, 0.f};

#pragma unroll
    for (int kc = 0; kc < 4; ++kc)
#pragma unroll
        for (int nt = 0; nt < 4; ++nt)
            acc[nt] = __builtin_amdgcn_mfma_f32_16x16x32_bf16(af[kc].v, bf[nt][kc].v,
                                                              acc[nt], 0, 0, 0);

    // epilogue: rows base+quad*4+{0..3}; deg int4 (reads past deg end are
    // inside workspace -> safe; stores guarded)
    const int4 dg = *(const int4*)&deg[base + quad * 4];
    float dn[4];
    dn[0] = rsqrtf((float)dg.x + 1.f);
    dn[1] = rsqrtf((float)dg.y + 1.f);
    dn[2] = rsqrtf((float)dg.z + 1.f);
    dn[3] = rsqrtf((float)dg.w + 1.f);

#pragma unroll
    for (int r = 0; r < 4; ++r) {
        const int orow = base + quad * 4 + r;
        if (orow < N_NODES) {
#pragma unroll
            for (int nt = 0; nt < 4; ++nt)
                hb[(size_t)orow * HIDDEN + nt * 16 + m15] = f2bf(acc[nt][r] * dn[r]);
        }
    }
}

// ---------------------------------------------------------------------------
// K2: fused aggregate — one block per 256-node bucket, 256x64 fp32 LDS
// accumulator. ROUND-5 FIX: the edge loop is now BATCHED — each 8-lane group
// loads 8 consecutive edge records at once (coalesced), shfl-distributes,
// issues all 8 independent 128B hb gathers back-to-back (ILP), then does the
// masked LDS atomic adds. Round-4's one-edge-at-a-time cursor serialized a
// full memory latency per edge (710 us, 1.9% HBM).
// ---------------------------------------------------------------------------
__global__ __launch_bounds__(512) void k_agg(const int* __restrict__ offs,
                                             const int* __restrict__ src_tmp,
                                             const unsigned char* __restrict__ dst8,
                                             const ushort16* __restrict__ hb,
                                             const int* __restrict__ deg,
                                             const float* __restrict__ bias,
                                             const int* __restrict__ batch,
                                             float* __restrict__ u) {
    __shared__ float sacc[256 * 65];    // 66.56 KB, stride 65 breaks bank aliasing
    __shared__ int   segb[NCHUNK];
    __shared__ int   slen[NCHUNK];
    __shared__ int   gbs[256];
    __shared__ float sdn[256];
    const int b  = blockIdx.x;
    const int lo = b << BSHIFT;
    const int t  = threadIdx.x;

    if (t < NCHUNK) {
        const int s0 = offs[t * OFFS_W + b];
        segb[t] = s0;
        slen[t] = offs[t * OFFS_W + b + 1] - s0;
    }
    for (int i = t; i < 256 * 65; i += 512) sacc[i] = 0.f;
    if (t < 256) {
        const int node = lo + t;
        const bool ok = node < N_NODES;
        gbs[t] = ok ? batch[node] : 0;
        sdn[t] = ok ? rsqrtf((float)deg[node] + 1.f) : 0.f;
    }
    __syncthreads();

    // ---- edge loop: group g (8 lanes, within one wave) walks chunks
    //      g, g+64, ...; 8 edges in flight per batch.
    const int wv   = t >> 6;
    const int lane = t & 63;
    const int k    = lane & 7;
    const int kb   = lane & 56;                // shfl source base (in-wave)
    const int g    = wv * 8 + (lane >> 3);     // 0..63

    for (int c = g; c < NCHUNK; c += 64) {
        const int s0 = segb[c];
        const int L  = slen[c];
        for (int i = 0; i < L; i += 8) {
            const int idx = s0 + min(i + k, L - 1);   // clamped, coalesced
            const int sv = src_tmp[idx];
            const int dv = dst8[idx];

            uint4 v[8];
            int   dj[8];
#pragma unroll
            for (int j = 0; j < 8; ++j) {             // 8 independent gathers
                const int sj = __shfl(sv, kb | j);
                dj[j] = __shfl(dv, kb | j);
                v[j] = *(const uint4*)&hb[(size_t)sj * HIDDEN + k * 8];
            }
            const int rem = L - i;
#pragma unroll
            for (int j = 0; j < 8; ++j) {
                if (j < rem) {
                    float* a = &sacc[dj[j] * 65 + k * 8];
                    atomicAdd(&a[0], __uint_as_float(v[j].x << 16));
                    atomicAdd(&a[1], __uint_as_float(v[j].x & 0xffff0000u));
                    atomicAdd(&a[2], __uint_as_float(v[j].y << 16));
                    atomicAdd(&a[3], __uint_as_float(v[j].y & 0xffff0000u));
                    atomicAdd(&a[4], __uint_as_float(v[j].z << 16));
                    atomicAdd(&a[5], __uint_as_float(v[j].z & 0xffff0000u));
                    atomicAdd(&a[6], __uint_as_float(v[j].w << 16));
                    atomicAdd(&a[7], __uint_as_float(v[j].w & 0xffff0000u));
                }
            }
        }
    }
    __syncthreads();

    // ---- epilogue: relu + pool. thread = (feature f, node-segment seg) ----
    const int f   = t & 63;
    const int seg = t >> 6;             // 0..7, 32 nodes each
    const unsigned short* hrow = (const unsigned short*)hb;
    const float bf_ = bias[f];
    float a = 0.f;
    int   cg = -1;
    for (int n = seg * 32; n < seg * 32 + 32; ++n) {
        const int node = lo + n;
        if (node >= N_NODES) break;
        const float self = __uint_as_float((uint32)hrow[(size_t)node * HIDDEN + f] << 16);
        const float r = fmaxf(fmaf(sacc[n * 65 + f] + self, sdn[n], bf_), 0.f);
        const int gr = gbs[n];
        if (gr != cg) {
            if (cg >= 0) atomicAdd(&u[cg * HIDDEN + f], a);
            cg = gr; a = r;
        } else {
            a += r;
        }
    }
    if (cg >= 0) atomicAdd(&u[cg * HIDDEN + f], a);
}

// ---------------------------------------------------------------------------
// K3: out[g] = relu(u[g] @ W1 + b1) @ W2 + b2
// ---------------------------------------------------------------------------
__global__ __launch_bounds__(64) void mlp_kernel(const float* __restrict__ u,
                                                 const float* __restrict__ W1,
                                                 const float* __restrict__ b1,
                                                 const float* __restrict__ W2,
                                                 const float* __restrict__ b2,
                                                 float* __restrict__ out) {
    __shared__ float W1s[HIDDEN * 16];
    __shared__ float W2s[16];
    __shared__ float b1s[16];
    const int t = threadIdx.x;
    for (int i = t; i < HIDDEN * 16; i += 64) W1s[i] = W1[i];
    if (t < 16) { W2s[t] = W2[t]; b1s[t] = b1[t]; }
    __syncthreads();
    if (t < NUM_GRAPHS) {
        float uu[HIDDEN];
#pragma unroll
        for (int k = 0; k < HIDDEN; ++k) uu[k] = u[t * HIDDEN + k];
        float o = b2[0];
#pragma unroll
        for (int j = 0; j < 16; ++j) {
            float s = b1s[j];
#pragma unroll
            for (int k = 0; k < HIDDEN; ++k) s = fmaf(uu[k], W1s[k * 16 + j], s);
            o = fmaf(fmaxf(s, 0.f), W2s[j], o);
        }
        out[t] = o;
    }
}

// ---------------------------------------------------------------------------
extern "C" void kernel_launch(void* const* d_in, const int* in_sizes, int n_in,
                              void* d_out, int out_size, void* d_ws, size_t ws_size,
                              hipStream_t stream) {
    const float* x  = (const float*)d_in[0];
    const float* W  = (const float*)d_in[1];
    const float* b  = (const float*)d_in[2];
    const float* W1 = (const float*)d_in[3];
    const float* b1 = (const float*)d_in[4];
    const float* W2 = (const float*)d_in[5];
    const float* b2 = (const float*)d_in[6];
    const int*   ei = (const int*)d_in[7];     // [2, E] flat
    const int* batch = (const int*)d_in[8];    // [N], sorted
    float* out = (float*)d_out;

    ushort16* hb       = (ushort16*)d_ws;                        // 12.8 MB
    int*      src_tmp  = (int*)(hb + (size_t)N_NODES * HIDDEN);  // 6.4 MB
    unsigned char* dst8 = (unsigned char*)(src_tmp + N_EDGES);   // 1.6 MB
    int*      offs     = (int*)(dst8 + N_EDGES);                 // 613 KB
    float*    u        = (float*)(offs + NCHUNK * OFFS_W);       // 16 KB
    int*      deg      = (int*)(u + NUM_GRAPHS * HIDDEN);        // 400 KB
    ushort16* Wtg      = (ushort16*)(deg + N_NODES);             // 16 KB

    // zero u (pool accumulators) + deg (atomic degree counters) in one memset
    hipMemsetAsync(u, 0, (NUM_GRAPHS * HIDDEN + N_NODES) * sizeof(float), stream);

    k_pre<<<WT_BLOCKS + NCHUNK, 512, 0, stream>>>(W, Wtg, ei, src_tmp, dst8, offs, deg);
    k_gemm<<<GEMM_GRID, 512, 0, stream>>>(x, Wtg, deg, hb);
    k_agg<<<NBUCKET, 512, 0, stream>>>(offs, src_tmp, dst8, hb, deg, b, batch, u);
    mlp_kernel<<<1, 64, 0, stream>>>(u, W1, b1, W2, b2, out);
}

// Round 6
// 246.488 us; speedup vs baseline: 3.6628x; 3.6202x over previous
//
#include <hip/hip_runtime.h>

#define N_NODES   100000
#define N_FEAT    128
#define N_EDGES   1600000
#define HIDDEN    64
#define NUM_GRAPHS 64
#define CHUNK   4096
#define NCHUNK  ((N_EDGES + CHUNK - 1) / CHUNK)   // 391 chunks of 4096 edges
#define BSHIFT  8
#define NBUCKET ((N_NODES + 255) >> 8)            // 391 buckets of 256 nodes
#define OFFS_W  (NBUCKET + 1)                     // 392 entries per chunk
#define CAP     4800                              // max edges per sort piece
#define QE      ((CAP + 511) / 512)               // 10 register-cache slots
#define WT_BLOCKS 4
#define GEMM_GRID ((N_NODES + 127) / 128)         // 782 blocks of 128 rows

typedef unsigned int  uint32;
typedef unsigned short ushort16;

typedef __attribute__((ext_vector_type(8))) __bf16 bf16x8;
typedef __attribute__((ext_vector_type(4))) float  f32x4;
union Frag8 { bf16x8 v; unsigned short s[8]; uint4 q; };

// fp32 -> bf16 round-to-nearest-even
static __device__ __forceinline__ unsigned short f2bf(float f) {
    uint32 u = __float_as_uint(f);
    u += 0x7fffu + ((u >> 16) & 1u);
    return (unsigned short)(u >> 16);
}

// ---------------------------------------------------------------------------
// L1: blocks [0,4)   : Wt[n][k] = bf16(W[k][n])
//     blocks [4,395) : partition edges into 391 dst-buckets per 4096-edge
//                      chunk via LDS; deg counted from the bucket-sorted
//                      writeout (L2-local RMW).
// ---------------------------------------------------------------------------
__global__ __launch_bounds__(512) void k_pre(const float* __restrict__ W,
                                             ushort16* __restrict__ Wt,
                                             const int* __restrict__ ei,
                                             int* __restrict__ src_out,
                                             unsigned char* __restrict__ dst8,
                                             int* __restrict__ offs,
                                             int* __restrict__ deg) {
    __shared__ int hist[512];
    __shared__ int excl[512];
    __shared__ int ssrc[CHUNK];     // 16 KB
    __shared__ int sdst[CHUNK];     // 16 KB

    if (blockIdx.x < WT_BLOCKS) {   // ---- w_transpose: 128*64 = 8192 elems
        const int base = blockIdx.x * 2048 + threadIdx.x;
#pragma unroll
        for (int j = 0; j < 4; ++j) {
            const int idx = base + j * 512;
            const int k = idx >> 6, n = idx & 63;
            Wt[n * N_FEAT + k] = f2bf(W[idx]);
        }
        return;
    }

    // ---- partition ----
    const int c = blockIdx.x - WT_BLOCKS;
    const int base = c * CHUNK;
    const int n = min(CHUNK, N_EDGES - base);   // always a multiple of 4
    const int t = threadIdx.x;
    hist[t] = 0;
    __syncthreads();

    int es[CHUNK / 512], ed[CHUNK / 512], rk[CHUNK / 512];
#pragma unroll
    for (int k = 0; k < CHUNK / 512; ++k) {
        const int i = t + k * 512;
        if (i < n) {
            ed[k] = __builtin_nontemporal_load(&ei[N_EDGES + base + i]);
            es[k] = __builtin_nontemporal_load(&ei[base + i]);
            rk[k] = atomicAdd(&hist[ed[k] >> BSHIFT], 1);
        }
    }
    __syncthreads();

    const int cnt = hist[t];
    for (int off = 1; off < 512; off <<= 1) {
        const int v = (t >= off) ? hist[t - off] : 0;
        __syncthreads();
        hist[t] += v;
        __syncthreads();
    }
    excl[t] = hist[t] - cnt;
    __syncthreads();
    if (t <= NBUCKET) offs[c * OFFS_W + t] = base + excl[t];   // excl[NBUCKET]==n

#pragma unroll
    for (int k = 0; k < CHUNK / 512; ++k) {
        const int i = t + k * 512;
        if (i < n) {
            const int pos = excl[ed[k] >> BSHIFT] + rk[k];
            ssrc[pos] = es[k];
            sdst[pos] = ed[k];
        }
    }
    __syncthreads();

    for (int i = t; i < n; i += 512) {
        src_out[base + i] = ssrc[i];
        atomicAdd(&deg[sdst[i]], 1);      // bucket-sorted order: L2-local RMW
    }
    for (int i = t * 4; i < n; i += 2048) {
        const uint32 p = (uint32)(sdst[i] & 255)
                       | ((uint32)(sdst[i + 1] & 255) << 8)
                       | ((uint32)(sdst[i + 2] & 255) << 16)
                       | ((uint32)(sdst[i + 3] & 255) << 24);
        *(uint32*)&dst8[base + i] = p;
    }
}

// ---------------------------------------------------------------------------
// K1: hb = bf16( (x @ W) * rsqrt(deg+1) )  — BW-bound MFMA gemm, dis scale
// fused into the epilogue.
// ---------------------------------------------------------------------------
__global__ __launch_bounds__(512) void k_gemm(const float* __restrict__ x,
                                              const ushort16* __restrict__ Wt,
                                              const int* __restrict__ deg,
                                              ushort16* __restrict__ hb) {
    const int t    = threadIdx.x;
    const int lane = t & 63;
    const int wv   = t >> 6;                              // 0..7
    const int m15  = lane & 15;
    const int quad = lane >> 4;
    const int base = blockIdx.x * 128 + wv * 16;
    const int arow = min(base + m15, N_NODES - 1);        // clamp tail

    const float* xr = &x[(size_t)arow * N_FEAT + quad * 8];
    float4 xa[4][2];
#pragma unroll
    for (int kc = 0; kc < 4; ++kc) {
        xa[kc][0] = *(const float4*)&xr[kc * 32];
        xa[kc][1] = *(const float4*)&xr[kc * 32 + 4];
    }

    Frag8 bf[4][4];
#pragma unroll
    for (int nt = 0; nt < 4; ++nt) {
        const ushort16* wr = &Wt[(nt * 16 + m15) * N_FEAT + quad * 8];
#pragma unroll
        for (int kc = 0; kc < 4; ++kc)
            bf[nt][kc].q = *(const uint4*)&wr[kc * 32];
    }

    Frag8 af[4];
#pragma unroll
    for (int kc = 0; kc < 4; ++kc) {
        const float* f = (const float*)&xa[kc][0];
#pragma unroll
        for (int j = 0; j < 8; ++j) af[kc].s[j] = f2bf(f[j]);
    }

    f32x4 acc[4];
#pragma unroll
    for (int nt = 0; nt < 4; ++nt) acc[nt] = (f32x4){0.f, 0.f, 0.f, 0.f};

#pragma unroll
    for (int kc = 0; kc < 4; ++kc)
#pragma unroll
        for (int nt = 0; nt < 4; ++nt)
            acc[nt] = __builtin_amdgcn_mfma_f32_16x16x32_bf16(af[kc].v, bf[nt][kc].v,
                                                              acc[nt], 0, 0, 0);

    const int4 dg = *(const int4*)&deg[base + quad * 4];
    float dn[4];
    dn[0] = rsqrtf((float)dg.x + 1.f);
    dn[1] = rsqrtf((float)dg.y + 1.f);
    dn[2] = rsqrtf((float)dg.z + 1.f);
    dn[3] = rsqrtf((float)dg.w + 1.f);

#pragma unroll
    for (int r = 0; r < 4; ++r) {
        const int orow = base + quad * 4 + r;
        if (orow < N_NODES) {
#pragma unroll
            for (int nt = 0; nt < 4; ++nt)
                hb[(size_t)orow * HIDDEN + nt * 16 + m15] = f2bf(acc[nt][r] * dn[r]);
        }
    }
}

// ---------------------------------------------------------------------------
// K2: fused CSR-sort + aggregate per 256-node bucket. ROUND-6: rounds 4/5
// bottomed at 714us on ds_atomic_add_f32 (102M lane-atomics); here the sort
// phase (int hist atomics, 1/edge — proven fast in bucket_csr) orders edges
// in LDS, and aggregation is pure REGISTER accumulation: 8-lane group owns
// 4 nodes, reads src ids from LDS (broadcast), 8 independent 128B gathers,
// FMA into acc[4][8]. Zero f32 atomics; no srcs global round-trip.
// ---------------------------------------------------------------------------
__global__ __launch_bounds__(512, 4) void k_csragg(const int* __restrict__ offs,
                                                   const int* __restrict__ src_tmp,
                                                   const unsigned char* __restrict__ dst8,
                                                   const ushort16* __restrict__ hb,
                                                   const int* __restrict__ deg,
                                                   const float* __restrict__ bias,
                                                   const int* __restrict__ batch,
                                                   float* __restrict__ u) {
    __shared__ float spbuf[256 * 65];   // 66.56 KB: ssrc (sort) then sp (pool)
    __shared__ int   segb[NCHUNK];
    __shared__ int   pre[NCHUNK + 1];
    __shared__ int   sc[512];
    __shared__ int   hist[256];
    __shared__ int   nxt[256];
    __shared__ int   cnt_s[256];
    __shared__ float sdn[256];
    __shared__ int   gbs[256];
    int* ssrc = (int*)spbuf;
    float* sp = spbuf;

    const int b  = blockIdx.x;
    const int lo = b << BSHIFT;
    const int t  = threadIdx.x;

    int len = 0;
    if (t < NCHUNK) {
        const int s0 = offs[t * OFFS_W + b];
        segb[t] = s0;
        len = offs[t * OFFS_W + b + 1] - s0;
    }
    sc[t] = len;
    if (t < 256) {
        const int node = lo + t;
        const bool ok = node < N_NODES;
        gbs[t] = ok ? batch[node] : 0;
        sdn[t] = ok ? rsqrtf((float)deg[node] + 1.f) : 0.f;
    }
    __syncthreads();
    for (int off = 1; off < 512; off <<= 1) {           // 512-wide scan of seg lens
        const int v = (t >= off) ? sc[t - off] : 0;
        __syncthreads();
        sc[t] += v;
        __syncthreads();
    }
    if (t == 0) pre[0] = 0;
    if (t < NCHUNK) pre[t + 1] = sc[t];
    __syncthreads();

    const int total = pre[NCHUNK];
    const int lane  = t & 63;
    const int k     = lane & 7;
    const int grp   = (t >> 6) * 8 + (lane >> 3);       // 0..63; nodes grp*4+a

    float acc[4][8];
#pragma unroll
    for (int a = 0; a < 4; ++a)
#pragma unroll
        for (int j = 0; j < 8; ++j) acc[a][j] = 0.f;

    // ---- piece loop (1 piece for this input; correct for any bucket size) ----
    int c0 = 0, e0 = 0;
    while (e0 < total) {
        int loC = c0, hiC = NCHUNK + 1;                 // largest c1: pre[c1]<=e0+CAP
        while (hiC - loC > 1) { const int mid = (loC + hiC) >> 1;
                                if (pre[mid] <= e0 + CAP) loC = mid; else hiC = mid; }
        const int c1 = loC;
        const int e1 = pre[c1];
        const int Tp = e1 - e0;

        if (t < 256) hist[t] = 0;
        __syncthreads();

        int es[QE], ed[QE], rk[QE];                     // static-indexed: no scratch
#pragma unroll
        for (int q = 0; q < QE; ++q) {
            const int e = t + q * 512;
            if (e < Tp) {
                const int eg = e0 + e;
                int l2 = c0, h2 = c1;
                while (h2 - l2 > 1) { const int mid = (l2 + h2) >> 1;
                                      if (pre[mid] <= eg) l2 = mid; else h2 = mid; }
                const int gidx = segb[l2] + (eg - pre[l2]);
                ed[q] = dst8[gidx];
                es[q] = src_tmp[gidx];
                rk[q] = atomicAdd(&hist[ed[q]], 1);     // int atomic, 1 per edge
            }
        }
        __syncthreads();

        const int cv = (t < 256) ? hist[t] : 0;
        for (int off = 1; off < 256; off <<= 1) {
            int v = 0;
            if (t < 256 && t >= off) v = hist[t - off];
            __syncthreads();
            if (t < 256) hist[t] += v;
            __syncthreads();
        }
        if (t < 256) { nxt[t] = hist[t] - cv; cnt_s[t] = cv; }
        __syncthreads();

#pragma unroll
        for (int q = 0; q < QE; ++q)
            if (t + q * 512 < Tp) ssrc[nxt[ed[q]] + rk[q]] = es[q];
        __syncthreads();

        // ---- register aggregation: group grp -> nodes grp*4 + a ----
#pragma unroll
        for (int a = 0; a < 4; ++a) {
            const int n   = grp * 4 + a;
            const int beg = nxt[n];
            const int L   = cnt_s[n];
            for (int i = 0; i < L; i += 8) {
                int sj[8];
#pragma unroll
                for (int j = 0; j < 8; ++j) sj[j] = ssrc[beg + min(i + j, L - 1)];
                uint4 v[8];
#pragma unroll
                for (int j = 0; j < 8; ++j)            // 8 independent 128B gathers
                    v[j] = *(const uint4*)&hb[(size_t)sj[j] * HIDDEN + k * 8];
                const int rem = L - i;
#pragma unroll
                for (int j = 0; j < 8; ++j) {
                    const float m = (j < rem) ? 1.f : 0.f;
                    acc[a][0] = fmaf(__uint_as_float(v[j].x << 16),         m, acc[a][0]);
                    acc[a][1] = fmaf(__uint_as_float(v[j].x & 0xffff0000u), m, acc[a][1]);
                    acc[a][2] = fmaf(__uint_as_float(v[j].y << 16),         m, acc[a][2]);
                    acc[a][3] = fmaf(__uint_as_float(v[j].y & 0xffff0000u), m, acc[a][3]);
                    acc[a][4] = fmaf(__uint_as_float(v[j].z << 16),         m, acc[a][4]);
                    acc[a][5] = fmaf(__uint_as_float(v[j].z & 0xffff0000u), m, acc[a][5]);
                    acc[a][6] = fmaf(__uint_as_float(v[j].w << 16),         m, acc[a][6]);
                    acc[a][7] = fmaf(__uint_as_float(v[j].w & 0xffff0000u), m, acc[a][7]);
                }
            }
        }
        __syncthreads();                                // ssrc reads done before reuse
        c0 = c1; e0 = e1;
    }

    // ---- epilogue: r = relu(dn*(acc + self) + b) in regs, stage to sp ----
    const float4 b0 = *(const float4*)&bias[k * 8];
    const float4 b1 = *(const float4*)&bias[k * 8 + 4];
#pragma unroll
    for (int a = 0; a < 4; ++a) {
        const int n = grp * 4 + a;
        const int node = lo + n;                        // OOB rows read workspace: safe
        const uint4 hv = *(const uint4*)&hb[(size_t)min(node, N_NODES - 1) * HIDDEN + k * 8];
        const float dn = sdn[n];
        float4 r0, r1;
        r0.x = fmaxf(fmaf(acc[a][0] + __uint_as_float(hv.x << 16),         dn, b0.x), 0.f);
        r0.y = fmaxf(fmaf(acc[a][1] + __uint_as_float(hv.x & 0xffff0000u), dn, b0.y), 0.f);
        r0.z = fmaxf(fmaf(acc[a][2] + __uint_as_float(hv.y << 16),         dn, b0.z), 0.f);
        r0.w = fmaxf(fmaf(acc[a][3] + __uint_as_float(hv.y & 0xffff0000u), dn, b0.w), 0.f);
        r1.x = fmaxf(fmaf(acc[a][4] + __uint_as_float(hv.z << 16),         dn, b1.x), 0.f);
        r1.y = fmaxf(fmaf(acc[a][5] + __uint_as_float(hv.z & 0xffff0000u), dn, b1.y), 0.f);
        r1.z = fmaxf(fmaf(acc[a][6] + __uint_as_float(hv.w << 16),         dn, b1.z), 0.f);
        r1.w = fmaxf(fmaf(acc[a][7] + __uint_as_float(hv.w & 0xffff0000u), dn, b1.w), 0.f);
        *(float4*)&sp[n * 65 + k * 8]     = r0;         // sp overlays ssrc (reads done)
        *(float4*)&sp[n * 65 + k * 8 + 4] = r1;
    }
    __syncthreads();

    // ---- run-compressed pooling (sorted batch): thread = (feat f, 32-node seg) ----
    const int f   = t & 63;
    const int seg = t >> 6;
    float a = 0.f;
    int   cg = -1;
    for (int n = seg * 32; n < seg * 32 + 32; ++n) {
        const int node = lo + n;
        if (node >= N_NODES) break;
        const float r = sp[n * 65 + f];
        const int gr = gbs[n];
        if (gr != cg) {
            if (cg >= 0) atomicAdd(&u[cg * HIDDEN + f], a);
            cg = gr; a = r;
        } else {
            a += r;
        }
    }
    if (cg >= 0) atomicAdd(&u[cg * HIDDEN + f], a);
}

// ---------------------------------------------------------------------------
// K3: out[g] = relu(u[g] @ W1 + b1) @ W2 + b2
// ---------------------------------------------------------------------------
__global__ __launch_bounds__(64) void mlp_kernel(const float* __restrict__ u,
                                                 const float* __restrict__ W1,
                                                 const float* __restrict__ b1,
                                                 const float* __restrict__ W2,
                                                 const float* __restrict__ b2,
                                                 float* __restrict__ out) {
    __shared__ float W1s[HIDDEN * 16];
    __shared__ float W2s[16];
    __shared__ float b1s[16];
    const int t = threadIdx.x;
    for (int i = t; i < HIDDEN * 16; i += 64) W1s[i] = W1[i];
    if (t < 16) { W2s[t] = W2[t]; b1s[t] = b1[t]; }
    __syncthreads();
    if (t < NUM_GRAPHS) {
        float uu[HIDDEN];
#pragma unroll
        for (int k = 0; k < HIDDEN; ++k) uu[k] = u[t * HIDDEN + k];
        float o = b2[0];
#pragma unroll
        for (int j = 0; j < 16; ++j) {
            float s = b1s[j];
#pragma unroll
            for (int k = 0; k < HIDDEN; ++k) s = fmaf(uu[k], W1s[k * 16 + j], s);
            o = fmaf(fmaxf(s, 0.f), W2s[j], o);
        }
        out[t] = o;
    }
}

// ---------------------------------------------------------------------------
extern "C" void kernel_launch(void* const* d_in, const int* in_sizes, int n_in,
                              void* d_out, int out_size, void* d_ws, size_t ws_size,
                              hipStream_t stream) {
    const float* x  = (const float*)d_in[0];
    const float* W  = (const float*)d_in[1];
    const float* b  = (const float*)d_in[2];
    const float* W1 = (const float*)d_in[3];
    const float* b1 = (const float*)d_in[4];
    const float* W2 = (const float*)d_in[5];
    const float* b2 = (const float*)d_in[6];
    const int*   ei = (const int*)d_in[7];     // [2, E] flat
    const int* batch = (const int*)d_in[8];    // [N], sorted
    float* out = (float*)d_out;

    ushort16* hb       = (ushort16*)d_ws;                        // 12.8 MB
    int*      src_tmp  = (int*)(hb + (size_t)N_NODES * HIDDEN);  // 6.4 MB
    unsigned char* dst8 = (unsigned char*)(src_tmp + N_EDGES);   // 1.6 MB
    int*      offs     = (int*)(dst8 + N_EDGES);                 // 613 KB
    float*    u        = (float*)(offs + NCHUNK * OFFS_W);       // 16 KB
    int*      deg      = (int*)(u + NUM_GRAPHS * HIDDEN);        // 400 KB
    ushort16* Wtg      = (ushort16*)(deg + N_NODES);             // 16 KB

    // zero u (pool accumulators) + deg (atomic degree counters) in one memset
    hipMemsetAsync(u, 0, (NUM_GRAPHS * HIDDEN + N_NODES) * sizeof(float), stream);

    k_pre<<<WT_BLOCKS + NCHUNK, 512, 0, stream>>>(W, Wtg, ei, src_tmp, dst8, offs, deg);
    k_gemm<<<GEMM_GRID, 512, 0, stream>>>(x, Wtg, deg, hb);
    k_csragg<<<NBUCKET, 512, 0, stream>>>(offs, src_tmp, dst8, hb, deg, b, batch, u);
    mlp_kernel<<<1, 64, 0, stream>>>(u, W1, b1, W2, b2, out);
}

// Round 8
// 191.678 us; speedup vs baseline: 4.7102x; 1.2859x over previous
//
#include <hip/hip_runtime.h>

#define N_NODES   100000
#define N_FEAT    128
#define N_EDGES   1600000
#define HIDDEN    64
#define NUM_GRAPHS 64
#define CHUNK   4096
#define NCHUNK  ((N_EDGES + CHUNK - 1) / CHUNK)   // 391 chunks of 4096 edges
#define BSHIFT  8
#define NBUCKET ((N_NODES + 255) >> 8)            // 391 buckets of 256 nodes
#define OFFS_W  (NBUCKET + 1)                     // 392 entries per chunk
#define CAP     4800                              // bucket mean 4092, sigma ~64
#define QE      ((CAP + 511) / 512)               // 10 register-cache slots
#define WT_BLOCKS 4
#define GEMM_GRID ((N_NODES + 127) / 128)         // 782 tiles of 128 rows

typedef unsigned int  uint32;
typedef unsigned short ushort16;

typedef __attribute__((ext_vector_type(8))) __bf16 bf16x8;
typedef __attribute__((ext_vector_type(4))) float  f32x4;
union Frag8 { bf16x8 v; unsigned short s[8]; uint4 q; };

// fp32 -> bf16 round-to-nearest-even
static __device__ __forceinline__ unsigned short f2bf(float f) {
    uint32 u = __float_as_uint(f);
    u += 0x7fffu + ((u >> 16) & 1u);
    return (unsigned short)(u >> 16);
}

// ---------------------------------------------------------------------------
// L1: blocks [0,4)   : Wt[n][k] = bf16(W[k][n])
//     blocks [4,395) : partition edges into 391 dst-buckets per 4096-edge
//                      chunk via LDS. NO global deg atomics (R4-R6's 1.6M
//                      cross-XCD atomics ~80us — deg now comes free from the
//                      bucket sort hist in k_mix).
// ---------------------------------------------------------------------------
__global__ __launch_bounds__(512) void k_pre(const float* __restrict__ W,
                                             ushort16* __restrict__ Wt,
                                             const int* __restrict__ ei,
                                             int* __restrict__ src_out,
                                             unsigned char* __restrict__ dst8,
                                             int* __restrict__ offs) {
    __shared__ int hist[512];
    __shared__ int excl[512];
    __shared__ int ssrc[CHUNK];     // 16 KB
    __shared__ int sdst[CHUNK];     // 16 KB

    if (blockIdx.x < WT_BLOCKS) {   // ---- w_transpose: 128*64 = 8192 elems
        const int base = blockIdx.x * 2048 + threadIdx.x;
#pragma unroll
        for (int j = 0; j < 4; ++j) {
            const int idx = base + j * 512;
            const int k = idx >> 6, n = idx & 63;
            Wt[n * N_FEAT + k] = f2bf(W[idx]);
        }
        return;
    }

    // ---- partition ----
    const int c = blockIdx.x - WT_BLOCKS;
    const int base = c * CHUNK;
    const int n = min(CHUNK, N_EDGES - base);   // always a multiple of 4
    const int t = threadIdx.x;
    hist[t] = 0;
    __syncthreads();

    int es[CHUNK / 512], ed[CHUNK / 512], rk[CHUNK / 512];
#pragma unroll
    for (int k = 0; k < CHUNK / 512; ++k) {
        const int i = t + k * 512;
        if (i < n) {
            ed[k] = __builtin_nontemporal_load(&ei[N_EDGES + base + i]);
            es[k] = __builtin_nontemporal_load(&ei[base + i]);
            rk[k] = atomicAdd(&hist[ed[k] >> BSHIFT], 1);
        }
    }
    __syncthreads();

    const int cnt = hist[t];
    for (int off = 1; off < 512; off <<= 1) {
        const int v = (t >= off) ? hist[t - off] : 0;
        __syncthreads();
        hist[t] += v;
        __syncthreads();
    }
    excl[t] = hist[t] - cnt;
    __syncthreads();
    if (t <= NBUCKET) offs[c * OFFS_W + t] = base + excl[t];   // excl[NBUCKET]==n

#pragma unroll
    for (int k = 0; k < CHUNK / 512; ++k) {
        const int i = t + k * 512;
        if (i < n) {
            const int pos = excl[ed[k] >> BSHIFT] + rk[k];
            ssrc[pos] = es[k];
            sdst[pos] = ed[k];
        }
    }
    __syncthreads();

    for (int i = t; i < n; i += 512)
        src_out[base + i] = ssrc[i];
    for (int i = t * 4; i < n; i += 2048) {
        const uint32 p = (uint32)(sdst[i] & 255)
                       | ((uint32)(sdst[i + 1] & 255) << 8)
                       | ((uint32)(sdst[i + 2] & 255) << 16)
                       | ((uint32)(sdst[i + 3] & 255) << 24);
        *(uint32*)&dst8[base + i] = p;
    }
}

// ---------------------------------------------------------------------------
// L2: blocks [0,391)      : bucket sort -> coalesced srcs + row_ptr/row_end
//                           + dis[node] = rsqrt(cnt+1) from the sort hist
//                           (deg with ZERO global atomics).
//     blocks [391,391+782): UNSCALED gemm hb = bf16(x @ W) — independent of
//                           the sort, overlaps it (round-2's proven pattern).
// ---------------------------------------------------------------------------
__global__ __launch_bounds__(512) void k_mix(const float* __restrict__ x,
                                             const ushort16* __restrict__ Wt,
                                             ushort16* __restrict__ hb,
                                             const int* __restrict__ offs,
                                             const int* __restrict__ src_tmp,
                                             const unsigned char* __restrict__ dst8,
                                             int* __restrict__ srcs,
                                             int* __restrict__ row_ptr,
                                             int* __restrict__ row_end,
                                             float* __restrict__ dis) {
    __shared__ int hist[256];
    __shared__ int nxt[256];
    __shared__ int segb[NCHUNK];
    __shared__ int pre[NCHUNK + 1];
    __shared__ int sc[512];
    __shared__ int ssrc[CAP];       // 18.75 KB staging
    __shared__ int sb;

    if (blockIdx.x >= NBUCKET) {    // ---- gemm: 128 rows per block ----
        const int t    = threadIdx.x;
        const int lane = t & 63;
        const int wv   = t >> 6;                              // 0..7
        const int m15  = lane & 15;
        const int quad = lane >> 4;
        const int base = (blockIdx.x - NBUCKET) * 128 + wv * 16;
        const int arow = min(base + m15, N_NODES - 1);        // clamp tail

        const float* xr = &x[(size_t)arow * N_FEAT + quad * 8];
        float4 xa[4][2];
#pragma unroll
        for (int kc = 0; kc < 4; ++kc) {
            xa[kc][0] = *(const float4*)&xr[kc * 32];
            xa[kc][1] = *(const float4*)&xr[kc * 32 + 4];
        }

        Frag8 bfr[4][4];
#pragma unroll
        for (int nt = 0; nt < 4; ++nt) {
            const ushort16* wr = &Wt[(nt * 16 + m15) * N_FEAT + quad * 8];
#pragma unroll
            for (int kc = 0; kc < 4; ++kc)
                bfr[nt][kc].q = *(const uint4*)&wr[kc * 32];
        }

        Frag8 af[4];
#pragma unroll
        for (int kc = 0; kc < 4; ++kc) {
            const float* f = (const float*)&xa[kc][0];
#pragma unroll
            for (int j = 0; j < 8; ++j) af[kc].s[j] = f2bf(f[j]);
        }

        f32x4 acc[4];
#pragma unroll
        for (int nt = 0; nt < 4; ++nt) acc[nt] = (f32x4){0.f, 0.f, 0.f, 0.f};

#pragma unroll
        for (int kc = 0; kc < 4; ++kc)
#pragma unroll
            for (int nt = 0; nt < 4; ++nt)
                acc[nt] = __builtin_amdgcn_mfma_f32_16x16x32_bf16(af[kc].v, bfr[nt][kc].v,
                                                                  acc[nt], 0, 0, 0);

#pragma unroll
        for (int r = 0; r < 4; ++r) {
            const int orow = base + quad * 4 + r;
            if (orow < N_NODES) {
#pragma unroll
                for (int nt = 0; nt < 4; ++nt)
                    hb[(size_t)orow * HIDDEN + nt * 16 + m15] = f2bf(acc[nt][r]);
            }
        }
        return;
    }

    // ---- bucket sort (round-3's proven bucket_csr) ----
    const int b = blockIdx.x;
    const int lo = b << BSHIFT;
    const int t = threadIdx.x;

    if (t < 256) hist[t] = 0;
    if (t == 0) sb = 0;
    __syncthreads();

    int len = 0;
    if (t < NCHUNK) {
        const int s0 = offs[t * OFFS_W + b];
        const int s1 = offs[t * OFFS_W + b + 1];
        segb[t] = s0;
        len = s1 - s0;
        atomicAdd(&sb, s0 - t * CHUNK);     // closed-form bucket_start
    }
    sc[t] = len;                             // 512-wide scan (NCHUNK=391)
    __syncthreads();
    for (int off = 1; off < 512; off <<= 1) {
        const int v = (t >= off) ? sc[t - off] : 0;
        __syncthreads();
        sc[t] += v;
        __syncthreads();
    }
    if (t == 0) pre[0] = 0;
    if (t < NCHUNK) pre[t + 1] = sc[t];
    __syncthreads();

    const int total  = pre[NCHUNK];
    const int bstart = sb;
    const bool fits  = (total <= CAP);      // block-uniform

    int es[QE], ed[QE], rk[QE];
    int ne = 0;
    if (fits) {
        for (int e = t; e < total; e += 512) {
            int l2 = 0, h2 = NCHUNK;
            while (h2 - l2 > 1) { const int mid = (l2 + h2) >> 1;
                                  if (pre[mid] <= e) l2 = mid; else h2 = mid; }
            const int gidx = segb[l2] + (e - pre[l2]);
            const int d = dst8[gidx];
            const int s = src_tmp[gidx];
            es[ne] = s; ed[ne] = d;
            rk[ne] = atomicAdd(&hist[d], 1);
            ++ne;
        }
    } else {                                 // fallback: count pass (rare)
        const int lane = t & 63, wv = t >> 6;
        for (int c = wv; c < NCHUNK; c += 8)
            for (int i = segb[c] + lane; i < segb[c] + (pre[c + 1] - pre[c]); i += 64)
                atomicAdd(&hist[dst8[i]], 1);
    }
    __syncthreads();

    const int cnt = (t < 256) ? hist[t] : 0;
    for (int off = 1; off < 256; off <<= 1) {
        int v = 0;
        if (t < 256 && t >= off) v = hist[t - off];
        __syncthreads();
        if (t < 256) hist[t] += v;
        __syncthreads();
    }
    if (t < 256) {
        const int excl = hist[t] - cnt;
        nxt[t] = excl;
        const int node = lo + t;
        if (node < N_NODES) {
            row_ptr[node] = bstart + excl;
            row_end[node] = bstart + excl + cnt;
            dis[node]     = rsqrtf((float)cnt + 1.0f);   // deg, no atomics
        }
    }
    __syncthreads();

    if (fits) {
        for (int k = 0; k < ne; ++k)
            ssrc[nxt[ed[k]] + rk[k]] = es[k];   // LDS scatter
        __syncthreads();
        for (int i = t; i < total; i += 512)    // coalesced writeout
            srcs[bstart + i] = ssrc[i];
    } else {
        const int lane = t & 63, wv = t >> 6;
        for (int c = wv; c < NCHUNK; c += 8)
            for (int i = segb[c] + lane; i < segb[c] + (pre[c + 1] - pre[c]); i += 64) {
                const int d = dst8[i];
                const int pos = atomicAdd(&nxt[d], 1);
                srcs[bstart + pos] = src_tmp[i];
            }
    }
}

// ---------------------------------------------------------------------------
// L3: gather-aggregate, register accumulators (R6's fast structure, no f32
// LDS atomics). 8-lane group owns 4 nodes; per batch: 1 coalesced srcs load
// + shfl-distribute, 8 independent 128B hb gathers + ILP-parallel 4B
// dis[src] gathers; acc += h[src]*dis[src].
// Epilogue relu(dn*(acc + dn*h_self)+b); pooling via HALF-sized LDS stage
// (2 passes, 33KB) to keep occupancy up.
// ---------------------------------------------------------------------------
__global__ __launch_bounds__(512) void k_agg(const int* __restrict__ rp_g,
                                             const int* __restrict__ re_g,
                                             const int* __restrict__ srcs,
                                             const ushort16* __restrict__ hb,
                                             const float* __restrict__ dis,
                                             const float* __restrict__ bias,
                                             const int* __restrict__ batch,
                                             float* __restrict__ u) {
    __shared__ float sp[128 * 65];      // 33.3 KB staging (half the bucket)
    __shared__ int   rp[256];
    __shared__ int   rc[256];
    __shared__ float sdn[256];
    __shared__ int   gbs[256];
    const int b  = blockIdx.x;
    const int lo = b << BSHIFT;
    const int t  = threadIdx.x;

    if (t < 256) {
        const int node = lo + t;
        const bool ok = node < N_NODES;
        const int p = ok ? rp_g[node] : 0;
        rp[t]  = p;
        rc[t]  = ok ? (re_g[node] - p) : 0;
        sdn[t] = ok ? dis[node] : 0.f;
        gbs[t] = ok ? batch[node] : 0;
    }
    __syncthreads();

    const int lane = t & 63;
    const int k    = lane & 7;
    const int kb   = lane & 56;
    const int grp  = (t >> 6) * 8 + (lane >> 3);       // 0..63; nodes grp*4+a

    float acc[4][8];
#pragma unroll
    for (int a = 0; a < 4; ++a)
#pragma unroll
        for (int j = 0; j < 8; ++j) acc[a][j] = 0.f;

#pragma unroll
    for (int a = 0; a < 4; ++a) {
        const int n   = grp * 4 + a;
        const int beg = rp[n];
        const int L   = rc[n];
        for (int i = 0; i < L; i += 8) {
            const int idx = beg + min(i + k, L - 1);   // coalesced within group
            const int sv  = srcs[idx];
            const float wv_ = dis[sv];                 // 4B gather, L2-resident
            uint4 v[8];
            float w[8];
#pragma unroll
            for (int j = 0; j < 8; ++j) {              // 8 independent gathers
                const int sj = __shfl(sv, kb | j);
                w[j] = __shfl(wv_, kb | j);
                v[j] = *(const uint4*)&hb[(size_t)sj * HIDDEN + k * 8];
            }
            const int rem = L - i;
#pragma unroll
            for (int j = 0; j < 8; ++j) {
                const float m = (j < rem) ? w[j] : 0.f;
                acc[a][0] = fmaf(__uint_as_float(v[j].x << 16),         m, acc[a][0]);
                acc[a][1] = fmaf(__uint_as_float(v[j].x & 0xffff0000u), m, acc[a][1]);
                acc[a][2] = fmaf(__uint_as_float(v[j].y << 16),         m, acc[a][2]);
                acc[a][3] = fmaf(__uint_as_float(v[j].y & 0xffff0000u), m, acc[a][3]);
                acc[a][4] = fmaf(__uint_as_float(v[j].z << 16),         m, acc[a][4]);
                acc[a][5] = fmaf(__uint_as_float(v[j].z & 0xffff0000u), m, acc[a][5]);
                acc[a][6] = fmaf(__uint_as_float(v[j].w << 16),         m, acc[a][6]);
                acc[a][7] = fmaf(__uint_as_float(v[j].w & 0xffff0000u), m, acc[a][7]);
            }
        }
    }

    // ---- epilogue + pooling, two 128-node halves ----
    const float4 b0 = *(const float4*)&bias[k * 8];
    const float4 b1 = *(const float4*)&bias[k * 8 + 4];
    const int f   = t & 63;
    const int seg = t >> 6;                 // 0..7, 16 nodes each (per half)

    for (int h = 0; h < 2; ++h) {
        if ((grp >> 5) == h) {              // groups of this half stage r
#pragma unroll
            for (int a = 0; a < 4; ++a) {
                const int n = grp * 4 + a;
                const int nl = n - h * 128;
                const uint4 hv = *(const uint4*)
                    &hb[(size_t)min(lo + n, N_NODES - 1) * HIDDEN + k * 8];
                const float dn = sdn[n];
                float4 r0, r1;
                r0.x = fmaxf(fmaf(fmaf(__uint_as_float(hv.x << 16),         dn, acc[a][0]), dn, b0.x), 0.f);
                r0.y = fmaxf(fmaf(fmaf(__uint_as_float(hv.x & 0xffff0000u), dn, acc[a][1]), dn, b0.y), 0.f);
                r0.z = fmaxf(fmaf(fmaf(__uint_as_float(hv.y << 16),         dn, acc[a][2]), dn, b0.z), 0.f);
                r0.w = fmaxf(fmaf(fmaf(__uint_as_float(hv.y & 0xffff0000u), dn, acc[a][3]), dn, b0.w), 0.f);
                r1.x = fmaxf(fmaf(fmaf(__uint_as_float(hv.z << 16),         dn, acc[a][4]), dn, b1.x), 0.f);
                r1.y = fmaxf(fmaf(fmaf(__uint_as_float(hv.z & 0xffff0000u), dn, acc[a][5]), dn, b1.y), 0.f);
                r1.z = fmaxf(fmaf(fmaf(__uint_as_float(hv.w << 16),         dn, acc[a][6]), dn, b1.z), 0.f);
                r1.w = fmaxf(fmaf(fmaf(__uint_as_float(hv.w & 0xffff0000u), dn, acc[a][7]), dn, b1.w), 0.f);
                *(float4*)&sp[nl * 65 + k * 8]     = r0;
                *(float4*)&sp[nl * 65 + k * 8 + 4] = r1;
            }
        }
        __syncthreads();

        float a_ = 0.f;
        int   cg = -1;
        for (int n2 = seg * 16; n2 < seg * 16 + 16; ++n2) {
            const int node = lo + h * 128 + n2;
            if (node >= N_NODES) break;
            const float r = sp[n2 * 65 + f];
            const int gr = gbs[h * 128 + n2];
            if (gr != cg) {
                if (cg >= 0) atomicAdd(&u[cg * HIDDEN + f], a_);
                cg = gr; a_ = r;
            } else {
                a_ += r;
            }
        }
        if (cg >= 0) atomicAdd(&u[cg * HIDDEN + f], a_);
        __syncthreads();                    // before half 1 overwrites sp
    }
}

// ---------------------------------------------------------------------------
// K3: out[g] = relu(u[g] @ W1 + b1) @ W2 + b2
// ---------------------------------------------------------------------------
__global__ __launch_bounds__(64) void mlp_kernel(const float* __restrict__ u,
                                                 const float* __restrict__ W1,
                                                 const float* __restrict__ b1,
                                                 const float* __restrict__ W2,
                                                 const float* __restrict__ b2,
                                                 float* __restrict__ out) {
    __shared__ float W1s[HIDDEN * 16];
    __shared__ float W2s[16];
    __shared__ float b1s[16];
    const int t = threadIdx.x;
    for (int i = t; i < HIDDEN * 16; i += 64) W1s[i] = W1[i];
    if (t < 16) { W2s[t] = W2[t]; b1s[t] = b1[t]; }
    __syncthreads();
    if (t < NUM_GRAPHS) {
        float uu[HIDDEN];
#pragma unroll
        for (int k = 0; k < HIDDEN; ++k) uu[k] = u[t * HIDDEN + k];
        float o = b2[0];
#pragma unroll
        for (int j = 0; j < 16; ++j) {
            float s = b1s[j];
#pragma unroll
            for (int k = 0; k < HIDDEN; ++k) s = fmaf(uu[k], W1s[k * 16 + j], s);
            o = fmaf(fmaxf(s, 0.f), W2s[j], o);
        }
        out[t] = o;
    }
}

// ---------------------------------------------------------------------------
extern "C" void kernel_launch(void* const* d_in, const int* in_sizes, int n_in,
                              void* d_out, int out_size, void* d_ws, size_t ws_size,
                              hipStream_t stream) {
    const float* x  = (const float*)d_in[0];
    const float* W  = (const float*)d_in[1];
    const float* b  = (const float*)d_in[2];
    const float* W1 = (const float*)d_in[3];
    const float* b1 = (const float*)d_in[4];
    const float* W2 = (const float*)d_in[5];
    const float* b2 = (const float*)d_in[6];
    const int*   ei = (const int*)d_in[7];     // [2, E] flat
    const int* batch = (const int*)d_in[8];    // [N], sorted
    float* out = (float*)d_out;

    ushort16* hb       = (ushort16*)d_ws;                        // 12.8 MB
    int*      src_tmp  = (int*)(hb + (size_t)N_NODES * HIDDEN);  // 6.4 MB
    unsigned char* dst8 = (unsigned char*)(src_tmp + N_EDGES);   // 1.6 MB
    int*      srcs     = (int*)(dst8 + N_EDGES);                 // 6.4 MB
    int*      offs     = srcs + N_EDGES;                         // 613 KB
    int*      row_ptr  = offs + NCHUNK * OFFS_W;                 // 400 KB
    int*      row_end  = row_ptr + N_NODES;                      // 400 KB
    float*    dis      = (float*)(row_end + N_NODES);            // 400 KB
    float*    u        = dis + N_NODES;                          // 16 KB
    ushort16* Wtg      = (ushort16*)(u + NUM_GRAPHS * HIDDEN);   // 16 KB

    hipMemsetAsync(u, 0, NUM_GRAPHS * HIDDEN * sizeof(float), stream);

    k_pre<<<WT_BLOCKS + NCHUNK, 512, 0, stream>>>(W, Wtg, ei, src_tmp, dst8, offs);
    k_mix<<<NBUCKET + GEMM_GRID, 512, 0, stream>>>(x, Wtg, hb, offs, src_tmp, dst8,
                                                   srcs, row_ptr, row_end, dis);
    k_agg<<<NBUCKET, 512, 0, stream>>>(row_ptr, row_end, srcs, hb, dis, b, batch, u);
    mlp_kernel<<<1, 64, 0, stream>>>(u, W1, b1, W2, b2, out);
}

// Round 9
// 177.297 us; speedup vs baseline: 5.0922x; 1.0811x over previous
//
#include <hip/hip_runtime.h>

#define N_NODES   100000
#define N_FEAT    128
#define N_EDGES   1600000
#define HIDDEN    64
#define NUM_GRAPHS 64
#define CHUNK   4096
#define NCHUNK  ((N_EDGES + CHUNK - 1) / CHUNK)   // 391 chunks of 4096 edges
#define BSHIFT  8
#define NBUCKET ((N_NODES + 255) >> 8)            // 391 buckets of 256 nodes
#define OFFS_W  (NBUCKET + 1)                     // 392 entries per chunk
#define CAP     4800                              // bucket mean 4092, sigma ~64
#define QE      ((CAP + 511) / 512)               // 10 register slots (static idx)
#define WT_BLOCKS 4
#define GEMM_GRID ((N_NODES + 127) / 128)         // 782 tiles of 128 rows
#define AGG_NODES 64
#define AGG_BLOCKS ((N_NODES + AGG_NODES - 1) / AGG_NODES)   // 1563

typedef unsigned int  uint32;
typedef unsigned short ushort16;

typedef __attribute__((ext_vector_type(8))) __bf16 bf16x8;
typedef __attribute__((ext_vector_type(4))) float  f32x4;
union Frag8 { bf16x8 v; unsigned short s[8]; uint4 q; };

// fp32 -> bf16 round-to-nearest-even
static __device__ __forceinline__ unsigned short f2bf(float f) {
    uint32 u = __float_as_uint(f);
    u += 0x7fffu + ((u >> 16) & 1u);
    return (unsigned short)(u >> 16);
}

// inclusive scan of v across 512 threads; 2 barriers (vs 18 for LDS ladder)
static __device__ __forceinline__ int scan512(int v, int t, int* wsum) {
    const int lane = t & 63;
    const int wv   = t >> 6;
#pragma unroll
    for (int off = 1; off < 64; off <<= 1) {
        const int n = __shfl_up(v, off);
        if (lane >= off) v += n;
    }
    if (lane == 63) wsum[wv] = v;
    __syncthreads();
    if (t < 8) {
        int s = wsum[t];
#pragma unroll
        for (int off = 1; off < 8; off <<= 1) {
            const int n = __shfl_up(s, off);
            if (t >= off) s += n;
        }
        wsum[t] = s;
    }
    __syncthreads();
    if (wv > 0) v += wsum[wv - 1];
    return v;
}

// inclusive scan over the first 256 threads (4 waves); 2 barriers
static __device__ __forceinline__ int scan256(int v, int t, int* wsum) {
    const int lane = t & 63;
    const int wv   = t >> 6;
#pragma unroll
    for (int off = 1; off < 64; off <<= 1) {
        const int n = __shfl_up(v, off);
        if (lane >= off) v += n;
    }
    if (lane == 63 && wv < 4) wsum[wv] = v;
    __syncthreads();
    if (t < 4) {
        int s = wsum[t];
#pragma unroll
        for (int off = 1; off < 4; off <<= 1) {
            const int n = __shfl_up(s, off);
            if (t >= off) s += n;
        }
        wsum[t] = s;
    }
    __syncthreads();
    if (wv > 0 && wv < 4) v += wsum[wv - 1];
    return v;
}

// ---------------------------------------------------------------------------
// L1: blocks [0,4)   : Wt[n][k] = bf16(W[k][n])
//     blocks [4,395) : partition edges into 391 dst-buckets per 4096-edge
//                      chunk via LDS. Wave-scan (2 barriers, was 18).
// ---------------------------------------------------------------------------
__global__ __launch_bounds__(512) void k_pre(const float* __restrict__ W,
                                             ushort16* __restrict__ Wt,
                                             const int* __restrict__ ei,
                                             int* __restrict__ src_out,
                                             unsigned char* __restrict__ dst8,
                                             int* __restrict__ offs) {
    __shared__ int hist[512];
    __shared__ int excl[512];
    __shared__ int wsum[8];
    __shared__ int ssrc[CHUNK];     // 16 KB
    __shared__ int sdst[CHUNK];     // 16 KB

    if (blockIdx.x < WT_BLOCKS) {   // ---- w_transpose: 128*64 = 8192 elems
        const int base = blockIdx.x * 2048 + threadIdx.x;
#pragma unroll
        for (int j = 0; j < 4; ++j) {
            const int idx = base + j * 512;
            const int k = idx >> 6, n = idx & 63;
            Wt[n * N_FEAT + k] = f2bf(W[idx]);
        }
        return;
    }

    // ---- partition ----
    const int c = blockIdx.x - WT_BLOCKS;
    const int base = c * CHUNK;
    const int n = min(CHUNK, N_EDGES - base);   // always a multiple of 4
    const int t = threadIdx.x;
    hist[t] = 0;
    __syncthreads();

    int es[CHUNK / 512], ed[CHUNK / 512], rk[CHUNK / 512];
#pragma unroll
    for (int k = 0; k < CHUNK / 512; ++k) {
        const int i = t + k * 512;
        if (i < n) {
            ed[k] = __builtin_nontemporal_load(&ei[N_EDGES + base + i]);
            es[k] = __builtin_nontemporal_load(&ei[base + i]);
            rk[k] = atomicAdd(&hist[ed[k] >> BSHIFT], 1);
        }
    }
    __syncthreads();

    const int cnt = hist[t];
    const int inc = scan512(cnt, t, wsum);      // inclusive scan
    excl[t] = inc - cnt;
    __syncthreads();
    if (t <= NBUCKET) offs[c * OFFS_W + t] = base + excl[t];   // excl[NBUCKET]==n

#pragma unroll
    for (int k = 0; k < CHUNK / 512; ++k) {
        const int i = t + k * 512;
        if (i < n) {
            const int pos = excl[ed[k] >> BSHIFT] + rk[k];
            ssrc[pos] = es[k];
            sdst[pos] = ed[k];
        }
    }
    __syncthreads();

    for (int i = t; i < n; i += 512)
        src_out[base + i] = ssrc[i];
    for (int i = t * 4; i < n; i += 2048) {
        const uint32 p = (uint32)(sdst[i] & 255)
                       | ((uint32)(sdst[i + 1] & 255) << 8)
                       | ((uint32)(sdst[i + 2] & 255) << 16)
                       | ((uint32)(sdst[i + 3] & 255) << 24);
        *(uint32*)&dst8[base + i] = p;
    }
}

// ---------------------------------------------------------------------------
// L2: blocks [0,391)      : bucket sort -> srcs + row_ptr/row_end + dis.
//       R9: static-q register arrays (no scratch, rule #20), cmap table
//       (1 ds_read per edge, was 9-level dependent binary search),
//       wave-scans (2 barriers each, was 18).
//     blocks [391,391+782): UNSCALED gemm hb = bf16(x @ W), overlaps sort.
// ---------------------------------------------------------------------------
__global__ __launch_bounds__(512) void k_mix(const float* __restrict__ x,
                                             const ushort16* __restrict__ Wt,
                                             ushort16* __restrict__ hb,
                                             const int* __restrict__ offs,
                                             const int* __restrict__ src_tmp,
                                             const unsigned char* __restrict__ dst8,
                                             int* __restrict__ srcs,
                                             int* __restrict__ row_ptr,
                                             int* __restrict__ row_end,
                                             float* __restrict__ dis) {
    __shared__ int hist[256];
    __shared__ int nxt[256];
    __shared__ int segb[NCHUNK];
    __shared__ int pre[NCHUNK + 1];
    __shared__ unsigned short cmap[CAP];    // 9.4 KB: edge -> chunk id
    __shared__ int ssrc[CAP];               // 18.75 KB staging
    __shared__ int wsum[8];
    __shared__ int sb;

    if (blockIdx.x >= NBUCKET) {    // ---- gemm: 128 rows per block ----
        const int t    = threadIdx.x;
        const int lane = t & 63;
        const int wv   = t >> 6;                              // 0..7
        const int m15  = lane & 15;
        const int quad = lane >> 4;
        const int base = (blockIdx.x - NBUCKET) * 128 + wv * 16;
        const int arow = min(base + m15, N_NODES - 1);        // clamp tail

        const float* xr = &x[(size_t)arow * N_FEAT + quad * 8];
        float4 xa[4][2];
#pragma unroll
        for (int kc = 0; kc < 4; ++kc) {
            xa[kc][0] = *(const float4*)&xr[kc * 32];
            xa[kc][1] = *(const float4*)&xr[kc * 32 + 4];
        }

        Frag8 bfr[4][4];
#pragma unroll
        for (int nt = 0; nt < 4; ++nt) {
            const ushort16* wr = &Wt[(nt * 16 + m15) * N_FEAT + quad * 8];
#pragma unroll
            for (int kc = 0; kc < 4; ++kc)
                bfr[nt][kc].q = *(const uint4*)&wr[kc * 32];
        }

        Frag8 af[4];
#pragma unroll
        for (int kc = 0; kc < 4; ++kc) {
            const float* f = (const float*)&xa[kc][0];
#pragma unroll
            for (int j = 0; j < 8; ++j) af[kc].s[j] = f2bf(f[j]);
        }

        f32x4 acc[4];
#pragma unroll
        for (int nt = 0; nt < 4; ++nt) acc[nt] = (f32x4){0.f, 0.f, 0.f, 0.f};

#pragma unroll
        for (int kc = 0; kc < 4; ++kc)
#pragma unroll
            for (int nt = 0; nt < 4; ++nt)
                acc[nt] = __builtin_amdgcn_mfma_f32_16x16x32_bf16(af[kc].v, bfr[nt][kc].v,
                                                                  acc[nt], 0, 0, 0);

#pragma unroll
        for (int r = 0; r < 4; ++r) {
            const int orow = base + quad * 4 + r;
            if (orow < N_NODES) {
#pragma unroll
                for (int nt = 0; nt < 4; ++nt)
                    hb[(size_t)orow * HIDDEN + nt * 16 + m15] = f2bf(acc[nt][r]);
            }
        }
        return;
    }

    // ---- bucket sort ----
    const int b = blockIdx.x;
    const int lo = b << BSHIFT;
    const int t = threadIdx.x;

    if (t < 256) hist[t] = 0;
    if (t == 0) sb = 0;
    __syncthreads();

    int len = 0;
    if (t < NCHUNK) {
        const int s0 = offs[t * OFFS_W + b];
        const int s1 = offs[t * OFFS_W + b + 1];
        segb[t] = s0;
        len = s1 - s0;
        atomicAdd(&sb, s0 - t * CHUNK);     // closed-form bucket_start
    }
    const int inc = scan512(len, t, wsum);  // 2 barriers
    if (t == 0) pre[0] = 0;
    if (t < NCHUNK) pre[t + 1] = inc;
    __syncthreads();

    const int total  = pre[NCHUNK];
    const int bstart = sb;
    const bool fits  = (total <= CAP);      // block-uniform

    int es[QE], ed[QE], rk[QE];
    if (fits) {
        // build cmap: thread t stamps its chunk id over its edge range
        if (t < NCHUNK) {
            const int p0 = pre[t], p1 = pre[t + 1];
            for (int j = p0; j < p1; ++j) cmap[j] = (unsigned short)t;
        }
        __syncthreads();
#pragma unroll
        for (int q = 0; q < QE; ++q) {              // static idx: stays in VGPRs
            const int e = t + q * 512;
            if (e < total) {
                const int c2 = cmap[e];             // 1 LDS read (was 9-deep search)
                const int gidx = segb[c2] + (e - pre[c2]);
                ed[q] = dst8[gidx];
                es[q] = src_tmp[gidx];
                rk[q] = atomicAdd(&hist[ed[q]], 1);
            }
        }
    } else {                                 // fallback: count pass (rare)
        const int lane = t & 63, wv = t >> 6;
        for (int c2 = wv; c2 < NCHUNK; c2 += 8)
            for (int i = segb[c2] + lane; i < segb[c2] + (pre[c2 + 1] - pre[c2]); i += 64)
                atomicAdd(&hist[dst8[i]], 1);
    }
    __syncthreads();

    const int cv  = (t < 256) ? hist[t] : 0;
    const int hin = scan256(cv, t, wsum);    // 2 barriers
    if (t < 256) {
        const int excl = hin - cv;
        nxt[t] = excl;
        const int node = lo + t;
        if (node < N_NODES) {
            row_ptr[node] = bstart + excl;
            row_end[node] = bstart + excl + cv;
            dis[node]     = rsqrtf((float)cv + 1.0f);   // deg, zero global atomics
        }
    }
    __syncthreads();

    if (fits) {
#pragma unroll
        for (int q = 0; q < QE; ++q)
            if (t + q * 512 < total) ssrc[nxt[ed[q]] + rk[q]] = es[q];
        __syncthreads();
        for (int i = t; i < total; i += 512)    // coalesced writeout
            srcs[bstart + i] = ssrc[i];
    } else {
        const int lane = t & 63, wv = t >> 6;
        for (int c2 = wv; c2 < NCHUNK; c2 += 8)
            for (int i = segb[c2] + lane; i < segb[c2] + (pre[c2 + 1] - pre[c2]); i += 64) {
                const int d = dst8[i];
                const int pos = atomicAdd(&nxt[d], 1);
                srcs[bstart + pos] = src_tmp[i];
            }
    }
}

// ---------------------------------------------------------------------------
// L3: gather-aggregate. R9: 64 nodes/block, 1563 blocks x 256 threads
// (16.6 KB LDS -> ~6 blocks/CU) — fixes R8's 1.5-block/CU tail imbalance
// (Occupancy was 15%). 8-lane group owns 2 nodes; per batch: coalesced srcs
// load + dis gather, shfl-distribute, 8 independent 128B hb gathers, FMA.
// ---------------------------------------------------------------------------
__global__ __launch_bounds__(256) void k_agg(const int* __restrict__ rp_g,
                                             const int* __restrict__ re_g,
                                             const int* __restrict__ srcs,
                                             const ushort16* __restrict__ hb,
                                             const float* __restrict__ dis,
                                             const float* __restrict__ bias,
                                             const int* __restrict__ batch,
                                             float* __restrict__ u) {
    __shared__ float sp[AGG_NODES * 65];    // 16.6 KB
    __shared__ int   rp[AGG_NODES];
    __shared__ int   rc[AGG_NODES];
    __shared__ float sdn[AGG_NODES];
    __shared__ int   gbs[AGG_NODES];
    const int b  = blockIdx.x;
    const int lo = b * AGG_NODES;
    const int t  = threadIdx.x;

    if (t < AGG_NODES) {
        const int node = lo + t;
        const bool ok = node < N_NODES;
        const int p = ok ? rp_g[node] : 0;
        rp[t]  = p;
        rc[t]  = ok ? (re_g[node] - p) : 0;
        sdn[t] = ok ? dis[node] : 0.f;
        gbs[t] = ok ? batch[node] : 0;
    }
    __syncthreads();

    const int lane = t & 63;
    const int k    = lane & 7;
    const int kb   = lane & 56;
    const int grp  = (t >> 6) * 8 + (lane >> 3);       // 0..31; nodes grp*2+a

    float acc[2][8];
#pragma unroll
    for (int a = 0; a < 2; ++a)
#pragma unroll
        for (int j = 0; j < 8; ++j) acc[a][j] = 0.f;

#pragma unroll
    for (int a = 0; a < 2; ++a) {
        const int n   = grp * 2 + a;
        const int beg = rp[n];
        const int L   = rc[n];
        for (int i = 0; i < L; i += 8) {
            const int idx = beg + min(i + k, L - 1);   // coalesced within group
            const int sv  = srcs[idx];
            const float wv_ = dis[sv];                 // 4B gather, L2-resident
            uint4 v[8];
            float w[8];
#pragma unroll
            for (int j = 0; j < 8; ++j) {              // 8 independent gathers
                const int sj = __shfl(sv, kb | j);
                w[j] = __shfl(wv_, kb | j);
                v[j] = *(const uint4*)&hb[(size_t)sj * HIDDEN + k * 8];
            }
            const int rem = L - i;
#pragma unroll
            for (int j = 0; j < 8; ++j) {
                const float m = (j < rem) ? w[j] : 0.f;
                acc[a][0] = fmaf(__uint_as_float(v[j].x << 16),         m, acc[a][0]);
                acc[a][1] = fmaf(__uint_as_float(v[j].x & 0xffff0000u), m, acc[a][1]);
                acc[a][2] = fmaf(__uint_as_float(v[j].y << 16),         m, acc[a][2]);
                acc[a][3] = fmaf(__uint_as_float(v[j].y & 0xffff0000u), m, acc[a][3]);
                acc[a][4] = fmaf(__uint_as_float(v[j].z << 16),         m, acc[a][4]);
                acc[a][5] = fmaf(__uint_as_float(v[j].z & 0xffff0000u), m, acc[a][5]);
                acc[a][6] = fmaf(__uint_as_float(v[j].w << 16),         m, acc[a][6]);
                acc[a][7] = fmaf(__uint_as_float(v[j].w & 0xffff0000u), m, acc[a][7]);
            }
        }
    }

    // ---- epilogue: r = relu(dn*(acc + dn*h_self) + b), stage to sp ----
    const float4 b0 = *(const float4*)&bias[k * 8];
    const float4 b1 = *(const float4*)&bias[k * 8 + 4];
#pragma unroll
    for (int a = 0; a < 2; ++a) {
        const int n = grp * 2 + a;
        const uint4 hv = *(const uint4*)
            &hb[(size_t)min(lo + n, N_NODES - 1) * HIDDEN + k * 8];
        const float dn = sdn[n];
        float4 r0, r1;
        r0.x = fmaxf(fmaf(fmaf(__uint_as_float(hv.x << 16),         dn, acc[a][0]), dn, b0.x), 0.f);
        r0.y = fmaxf(fmaf(fmaf(__uint_as_float(hv.x & 0xffff0000u), dn, acc[a][1]), dn, b0.y), 0.f);
        r0.z = fmaxf(fmaf(fmaf(__uint_as_float(hv.y << 16),         dn, acc[a][2]), dn, b0.z), 0.f);
        r0.w = fmaxf(fmaf(fmaf(__uint_as_float(hv.y & 0xffff0000u), dn, acc[a][3]), dn, b0.w), 0.f);
        r1.x = fmaxf(fmaf(fmaf(__uint_as_float(hv.z << 16),         dn, acc[a][4]), dn, b1.x), 0.f);
        r1.y = fmaxf(fmaf(fmaf(__uint_as_float(hv.z & 0xffff0000u), dn, acc[a][5]), dn, b1.y), 0.f);
        r1.z = fmaxf(fmaf(fmaf(__uint_as_float(hv.w << 16),         dn, acc[a][6]), dn, b1.z), 0.f);
        r1.w = fmaxf(fmaf(fmaf(__uint_as_float(hv.w & 0xffff0000u), dn, acc[a][7]), dn, b1.w), 0.f);
        *(float4*)&sp[n * 65 + k * 8]     = r0;
        *(float4*)&sp[n * 65 + k * 8 + 4] = r1;
    }
    __syncthreads();

    // ---- run-compressed pooling (sorted batch): f = t&63, seg = t>>6 ----
    const int f   = t & 63;
    const int seg = t >> 6;                 // 0..3, 16 nodes each
    float a_ = 0.f;
    int   cg = -1;
    for (int n2 = seg * 16; n2 < seg * 16 + 16; ++n2) {
        const int node = lo + n2;
        if (node >= N_NODES) break;
        const float r = sp[n2 * 65 + f];
        const int gr = gbs[n2];
        if (gr != cg) {
            if (cg >= 0) atomicAdd(&u[cg * HIDDEN + f], a_);
            cg = gr; a_ = r;
        } else {
            a_ += r;
        }
    }
    if (cg >= 0) atomicAdd(&u[cg * HIDDEN + f], a_);
}

// ---------------------------------------------------------------------------
// K3: out[g] = relu(u[g] @ W1 + b1) @ W2 + b2
// ---------------------------------------------------------------------------
__global__ __launch_bounds__(64) void mlp_kernel(const float* __restrict__ u,
                                                 const float* __restrict__ W1,
                                                 const float* __restrict__ b1,
                                                 const float* __restrict__ W2,
                                                 const float* __restrict__ b2,
                                                 float* __restrict__ out) {
    __shared__ float W1s[HIDDEN * 16];
    __shared__ float W2s[16];
    __shared__ float b1s[16];
    const int t = threadIdx.x;
    for (int i = t; i < HIDDEN * 16; i += 64) W1s[i] = W1[i];
    if (t < 16) { W2s[t] = W2[t]; b1s[t] = b1[t]; }
    __syncthreads();
    if (t < NUM_GRAPHS) {
        float uu[HIDDEN];
#pragma unroll
        for (int k = 0; k < HIDDEN; ++k) uu[k] = u[t * HIDDEN + k];
        float o = b2[0];
#pragma unroll
        for (int j = 0; j < 16; ++j) {
            float s = b1s[j];
#pragma unroll
            for (int k = 0; k < HIDDEN; ++k) s = fmaf(uu[k], W1s[k * 16 + j], s);
            o = fmaf(fmaxf(s, 0.f), W2s[j], o);
        }
        out[t] = o;
    }
}

// ---------------------------------------------------------------------------
extern "C" void kernel_launch(void* const* d_in, const int* in_sizes, int n_in,
                              void* d_out, int out_size, void* d_ws, size_t ws_size,
                              hipStream_t stream) {
    const float* x  = (const float*)d_in[0];
    const float* W  = (const float*)d_in[1];
    const float* b  = (const float*)d_in[2];
    const float* W1 = (const float*)d_in[3];
    const float* b1 = (const float*)d_in[4];
    const float* W2 = (const float*)d_in[5];
    const float* b2 = (const float*)d_in[6];
    const int*   ei = (const int*)d_in[7];     // [2, E] flat
    const int* batch = (const int*)d_in[8];    // [N], sorted
    float* out = (float*)d_out;

    ushort16* hb       = (ushort16*)d_ws;                        // 12.8 MB
    int*      src_tmp  = (int*)(hb + (size_t)N_NODES * HIDDEN);  // 6.4 MB
    unsigned char* dst8 = (unsigned char*)(src_tmp + N_EDGES);   // 1.6 MB
    int*      srcs     = (int*)(dst8 + N_EDGES);                 // 6.4 MB
    int*      offs     = srcs + N_EDGES;                         // 613 KB
    int*      row_ptr  = offs + NCHUNK * OFFS_W;                 // 400 KB
    int*      row_end  = row_ptr + N_NODES;                      // 400 KB
    float*    dis      = (float*)(row_end + N_NODES);            // 400 KB
    float*    u        = dis + N_NODES;                          // 16 KB
    ushort16* Wtg      = (ushort16*)(u + NUM_GRAPHS * HIDDEN);   // 16 KB

    hipMemsetAsync(u, 0, NUM_GRAPHS * HIDDEN * sizeof(float), stream);

    k_pre<<<WT_BLOCKS + NCHUNK, 512, 0, stream>>>(W, Wtg, ei, src_tmp, dst8, offs);
    k_mix<<<NBUCKET + GEMM_GRID, 512, 0, stream>>>(x, Wtg, hb, offs, src_tmp, dst8,
                                                   srcs, row_ptr, row_end, dis);
    k_agg<<<AGG_BLOCKS, 256, 0, stream>>>(row_ptr, row_end, srcs, hb, dis, b, batch, u);
    mlp_kernel<<<1, 64, 0, stream>>>(u, W1, b1, W2, b2, out);
}